// Round 19
// baseline (171.073 us; speedup 1.0000x reference)
//
#include <hip/hip_runtime.h>
#include <math.h>

#define NCLS 21
#define NCO 20
#define STH 1024
#define RCAP 2048
#define RMAX 2000
#define LDSW 7680              // u64 capacity of the aliased LDS region (60 KB)
#define SCORE_THRESH 0.05f

typedef unsigned long long u64;
typedef unsigned int u32;
typedef unsigned short u16;

// Exact equivalent of (f32_div(inter,uni) > 0.3f):  inter > IOU_MID * uni in f64.
// 0.3f = 10066330*2^-25; midpoint to next float = 20132661*2^-26. RN tie at the
// midpoint rounds to even (0.3f) -> false, matching strict ">". 25b x 24b exact in f64.
#define IOU_MID (20132661.0 / 67108864.0)

__device__ __forceinline__ u64 readlane64(u64 v, int l) {
    u32 lo = (u32)__builtin_amdgcn_readlane((int)(u32)v, l);
    u32 hi = (u32)__builtin_amdgcn_readlane((int)(u32)(v >> 32), l);
    return ((u64)hi << 32) | lo;
}
__device__ __forceinline__ float readlanef(float v, int l) {
    return __uint_as_float((u32)__builtin_amdgcn_readlane((int)__float_as_uint(v), l));
}
__device__ __forceinline__ u64 shflxor64(u64 v, int m) {
    u32 lo = (u32)__shfl_xor((int)(u32)v, m, 64);
    u32 hi = (u32)__shfl_xor((int)(u32)(v >> 32), m, 64);
    return ((u64)hi << 32) | lo;
}

// Compact upper-triangle mask layout, per class:
// chunk ic (64 rows) starts at coff(ic); row (ic<<6)+il has W=nw-ic words
// (words v=ic..nw-1) at coff(ic) + il*W + (v-ic). Total = coff(nw) words.
__device__ __forceinline__ int coff(int ic, int nw) {
    return ((ic * nw - ((ic * (ic - 1)) >> 1)) << 6);
}

// Reference-exact box decode (absmax 0.0 through R1-R18).
__device__ __forceinline__ void decode_box(
    const float* __restrict__ rois, const float* __restrict__ loc,
    int r, int cls, float sh, float sw,
    float& by1, float& bx1, float& by2, float& bx2)
{
    float4 rb = *(const float4*)(rois + r * 4);
    float y1 = rb.x, x1 = rb.y, y2 = rb.z, x2 = rb.w;
    float h = y2 - y1, w = x2 - x1;
    float cy = y1 + 0.5f * h, cx = x1 + 0.5f * w;
    float4 l4 = *(const float4*)(loc + r * (NCLS * 4) + cls * 4);
    float dy = l4.x * 0.1f, dx = l4.y * 0.1f;
    float dh = l4.z * 0.2f, dw = l4.w * 0.2f;
    float ncy = dy * h + cy, ncx = dx * w + cx;
    float nh = expf(dh) * h, nw = expf(dw) * w;
    by1 = fminf(fmaxf(ncy - 0.5f * nh, 0.f), sh);
    bx1 = fminf(fmaxf(ncx - 0.5f * nw, 0.f), sw);
    by2 = fminf(fmaxf(ncy + 0.5f * nh, 0.f), sh);
    bx2 = fminf(fmaxf(ncx + 0.5f * nw, 0.f), sw);
}

// Reference-exact softmax prob (vectorized loads; float op ORDER k=0..20 kept
// identical to prior rounds: max then exp-sum in index order).
__device__ __forceinline__ float softmax_p(
    const float* __restrict__ scores, int r, int cls)
{
    const float* srow = scores + r * NCLS;
    float s[NCLS];
    float4 a0 = *(const float4*)(srow);
    float4 a1 = *(const float4*)(srow + 4);
    float4 a2 = *(const float4*)(srow + 8);
    float4 a3 = *(const float4*)(srow + 12);
    float4 a4 = *(const float4*)(srow + 16);
    s[0]=a0.x; s[1]=a0.y; s[2]=a0.z; s[3]=a0.w;
    s[4]=a1.x; s[5]=a1.y; s[6]=a1.z; s[7]=a1.w;
    s[8]=a2.x; s[9]=a2.y; s[10]=a2.z; s[11]=a2.w;
    s[12]=a3.x; s[13]=a3.y; s[14]=a3.z; s[15]=a3.w;
    s[16]=a4.x; s[17]=a4.y; s[18]=a4.z; s[19]=a4.w;
    s[20]=srow[20];
    float m = -INFINITY;
#pragma unroll
    for (int k = 0; k < NCLS; ++k) m = fmaxf(m, s[k]);
    float sum = 0.f, ec = 0.f;
#pragma unroll
    for (int k = 0; k < NCLS; ++k) {
        float e = expf(s[k] - m);
        sum += e;
        if (k == cls) ec = e;
    }
    return ec / sum;
}

// ---------------------------------------------------------------------------
// ONE kernel: 20 blocks x 1024 (one class per block). LDS phase-aliasing over
// a single 60 KB region (smem as u64[7680]):
//   Phase A/B (sort):   vkey = smem[0..2048)                       (16 KB)
//   Phase C/D (mask):   pb = (float4*)(smem+2048)  [16K..48K)      (32 KB)
//                       ar = (float*)(smem+6144)   [48K..56K)      ( 8 KB)
//                       vkey still live (roi idx source)
//   Phase E/F (resolve): mlds = smem[0..7680)                      (60 KB)
//                        (clobbers vkey+boxes; ord/global carries keys)
// All phase bodies are R13/R17/R18-proven verbatim; only residency changed.
// R11's fusion disaster is retro-explained (slow readlane rank + atomic
// compaction, both since replaced) — mask at 16 waves is ~4 us by census.
// ---------------------------------------------------------------------------
__global__ __launch_bounds__(STH) void fused_all_kernel(
    const float* __restrict__ loc, const float* __restrict__ scores,
    const float* __restrict__ rois, const int* __restrict__ ph,
    const int* __restrict__ pw, u64* __restrict__ ord,
    u64* __restrict__ M, float* __restrict__ out, int R)
{
    __shared__ u64 smem[LDSW];         // 60 KB aliased region
    __shared__ u64 keptw[32];
    __shared__ int cnt;
    const int t = threadIdx.x;
    const int c = blockIdx.x;          // class-1 index 0..19
    const int lane = t & 63;
    const float sh = (float)(*ph), sw = (float)(*pw);
    u64* vkey = smem;
    float4* pb = (float4*)(smem + 2048);
    float* ar = (float*)(smem + 6144);
    if (t == 0) cnt = 0;
    if (t < 32) keptw[t] = 0;
    __syncthreads();

    // ---- Phase A: softmax + ballot compaction (R18-proven). Active lanes
    // form a lane-prefix (r = t + k*1024), so lane 0 is a valid leader.
    for (int r = t; r < R; r += STH) {
        float p = softmax_p(scores, r, c + 1);
        bool valid = (p > SCORE_THRESH);
        u64 key = ((u64)(~__float_as_uint(p)) << 32) | (u32)r;
        u64 bal = __ballot(valid);
        if (bal) {
            int nb = (int)__popcll(bal);
            int base = 0;
            if (lane == 0) base = atomicAdd(&cnt, nb);
            base = __shfl(base, 0, 64);
            if (valid)
                vkey[base + (int)__popcll(bal & ((1ull << lane) - 1ull))] = key;
        }
    }
    __syncthreads();
    const int nv = cnt;
    const int nw = (nv + 63) >> 6;

    // ---- Phase B: rank via LDS same-address broadcast (R13-proven), then
    // in-place sorted scatter (register-buffered; R11-pattern) + ord write.
    u64 kjs[2]; int rks[2]; int nb2 = 0;
    for (int ibase = 0; ibase < nv; ibase += STH) {
        int i = ibase + t;
        u64 kj = 0; int rank = -1;
        if (i < nv) {
            kj = vkey[i];
            rank = 0;
#pragma unroll 4
            for (int j = 0; j < nv; ++j)
                rank += (vkey[j] < kj);
        }
        kjs[nb2] = kj; rks[nb2] = rank; ++nb2;
    }
    __syncthreads();                   // all ranking reads done
    for (int b = 0; b < nb2; ++b)
        if (rks[b] >= 0) {
            vkey[rks[b]] = kjs[b];
            ord[((size_t)c << 11) + rks[b]] = kjs[b];
        }
    __syncthreads();

    // ---- Phase C: decode sorted boxes to LDS.
    for (int i = t; i < nv; i += STH) {
        int r = (int)(u32)vkey[i];
        float a0, a1, a2, a3;
        decode_box(rois, loc, r, c + 1, sh, sw, a0, a1, a2, a3);
        pb[i] = make_float4(a0, a1, a2, a3);
        ar[i] = (a2 - a0) * (a3 - a1);
    }
    __syncthreads();

    // ---- Phase D: compact mask build (R17-verbatim body; 16 waves).
    const int wid = t >> 6;
    const int ntasks = nw * (nw + 1) / 2;
    u64* Mc = M + ((size_t)c << 16);
    for (int task = wid; task < ntasks; task += 16) {
        int ic = 0, rm = task;
        while (rm >= nw - ic) { rm -= nw - ic; ++ic; }  // uniform, <=32 iters
        int v = ic + rm;
        int i = (ic << 6) + lane;
        float4 a = pb[i];                    // garbage if i>=nv (not stored)
        float iarea = ar[i];
        float4 rj = pb[(v << 6) + lane];     // loads executed by all lanes
        float ja_l = ar[(v << 6) + lane];
        int jcnt = min(64, nv - (v << 6));
        u64 m = 0;
        for (int jj = 0; jj < jcnt; ++jj) {
            float jy1 = readlanef(rj.x, jj);
            float jx1 = readlanef(rj.y, jj);
            float jy2 = readlanef(rj.z, jj);
            float jx2 = readlanef(rj.w, jj);
            float ja  = readlanef(ja_l, jj);
            float ty1 = fmaxf(a.x, jy1);
            float tx1 = fmaxf(a.y, jx1);
            float ty2 = fminf(a.z, jy2);
            float tx2 = fminf(a.w, jx2);
            float inter = fmaxf(ty2 - ty1, 0.f) * fmaxf(tx2 - tx1, 0.f);
            float uni = fmaxf(iarea + ja - inter, 1e-10f);
            if ((double)inter > IOU_MID * (double)uni) m |= 1ull << jj;
        }
        if (v == ic) m &= (lane < 63) ? (~0ull << (lane + 1)) : 0ull;
        int W = nw - ic;
        if (i < nv) Mc[coff(ic, nw) + lane * W + (v - ic)] = m;
    }
    __syncthreads();                   // drains M stores (vmcnt(0) + barrier)

    // ---- Phase E: stage compact mask back (same-CU L1/L2-hot), aliased over
    // the whole region (vkey/boxes dead; ord carries keys).
    const int S = coff(nw, nw);
    const bool lds_ok = (S <= LDSW);
    if (lds_ok)
        for (int k = t; k < S; k += STH) smem[k] = Mc[k];
    __syncthreads();

    // ---- Phase F: resolve (R18-verbatim: ballot fixpoint + 8-wide batched
    // propagation), wave 0 only.
    if (t < 64) {
        auto core = [&](const auto* B) {
            u64 remreg = 0;                 // lane l owns removed-word l
            for (int w = 0; w < nw; ++w) {
                const int W = nw - w;
                const int cb = coff(w, nw);
                int i = (w << 6) + lane;
                u64 cw = (i < nv) ? B[cb + lane * W] : 0ull;   // diagonal word
                int remn = nv - (w << 6);
                u64 vb = (remn >= 64) ? ~0ull : ((1ull << remn) - 1ull);
                u64 cand = vb & ~readlane64(remreg, w);
                u64 X = cand;
                if (X) {
                    for (int it = 0; it < 64; ++it) {
                        u64 contrib = ((X >> lane) & 1ull) ? cw : 0ull;
#pragma unroll
                        for (int d = 1; d < 64; d <<= 1)
                            contrib |= shflxor64(contrib, d);
                        bool keep = ((cand >> lane) & 1ull) &&
                                    !((contrib >> lane) & 1ull);
                        u64 Xn = __ballot(keep);
                        if (Xn == X) break;
                        X = Xn;
                    }
                    if (lane == 0) keptw[w] = X;
                    bool lact = (lane > w) && (lane < nw);
                    u64 km = X, acc = 0;
                    while (km) {            // wave-uniform; 8-wide batches
                        int bs[8];
#pragma unroll
                        for (int g = 0; g < 8; ++g) {
                            bs[g] = km ? (__ffsll(km) - 1) : -1;
                            if (km) km &= km - 1;
                        }
                        u64 tmp[8];
#pragma unroll
                        for (int g = 0; g < 8; ++g)
                            tmp[g] = (bs[g] >= 0 && lact)
                                ? B[cb + bs[g] * W + (lane - w)] : 0ull;
#pragma unroll
                        for (int g = 0; g < 8; ++g) acc |= tmp[g];
                    }
                    if (lact) remreg |= acc;
                }
            }
        };
        if (lds_ok) core(smem); else core(Mc);
    }
    __syncthreads();

    // ---- Phase G: output — zero slice, barrier (drains), scatter kept rows
    // (ord is this block's own write: L1-hot).
    float* slice = out + (size_t)c * R * 5;
    for (int k = t; k < R * 5; k += STH) slice[k] = 0.f;
    __syncthreads();
    for (int i = t; i < nv; i += STH) {
        if ((keptw[i >> 6] >> (i & 63)) & 1ull) {
            u64 key = ord[((size_t)c << 11) + i];
            int r = (int)(u32)key;
            float v0, v1, v2, v3;
            decode_box(rois, loc, r, c + 1, sh, sw, v0, v1, v2, v3);
            float* p = slice + (size_t)r * 5;
            p[0] = v0; p[1] = v1; p[2] = v2; p[3] = v3;
            p[4] = __uint_as_float(~(u32)(key >> 32));
        }
    }
}

// --------------------------- fallback: R4 fused ----------------------------
#define NTH 1024
__global__ __launch_bounds__(NTH) void fused_kernel(
    const float* __restrict__ loc, const float* __restrict__ scores,
    const float* __restrict__ rois, const int* __restrict__ ph,
    const int* __restrict__ pw, float* __restrict__ out, int R)
{
    __shared__ u64 vkey[RMAX];
    __shared__ float2 p1[RMAX], p2[RMAX];
    __shared__ u64 chunk[64 * 33];
    __shared__ u64 rem[32];
    __shared__ int cnt;

    const int t = threadIdx.x;
    const int lane = t & 63;
    const int c = blockIdx.x + 1;
    const float sh = (float)(*ph), sw = (float)(*pw);

    if (t == 0) cnt = 0;
    if (t < 32) rem[t] = 0;
    __syncthreads();

    for (int r = t; r < R; r += NTH) {
        float p = softmax_p(scores, r, c);
        if (p > SCORE_THRESH) {
            int j = atomicAdd(&cnt, 1);
            vkey[j] = ((u64)(~__float_as_uint(p)) << 32) | (u32)r;
        }
    }
    __syncthreads();
    const int nv = cnt;
    const int nw = (nv + 63) >> 6;

    u64 kk0 = 0, kk1 = 0;
    int r0 = 0, r1 = 0;
    bool in0 = (t < nv), in1 = (t + NTH < nv);
    if (in0) kk0 = vkey[t];
    if (in1) kk1 = vkey[t + NTH];
#pragma unroll 8
    for (int i = 0; i < nv; ++i) {
        u64 k = vkey[i];
        r0 += (k < kk0);
        r1 += (k < kk1);
    }
    __syncthreads();

    for (int u = 0; u < 2; ++u) {
        bool act = u ? in1 : in0;
        if (act) {
            u64 kk = u ? kk1 : kk0;
            int rank = u ? r1 : r0;
            int r = (int)(kk & 0xffffffffu);
            float b0, b1, b2, b3;
            decode_box(rois, loc, r, c, sh, sw, b0, b1, b2, b3);
            vkey[rank] = kk;
            p1[rank] = make_float2(b0, b1);
            p2[rank] = make_float2(b2, b3);
        }
    }
    __syncthreads();

    for (int w = 0; w < nw; ++w) {
        int nwr = nw - w;
        u64 remw = rem[w];
        for (int task = t; task < (nwr << 6); task += NTH) {
            int vr = task >> 6, il = task & 63;
            int i = (w << 6) + il;
            u64 m = 0;
            if (i < nv && !((remw >> il) & 1ull)) {
                int v = w + vr;
                u64 rv = rem[v];
                if (~rv != 0ull) {
                    float2 a1 = p1[i], a2 = p2[i];
                    float iarea = (a2.x - a1.x) * (a2.y - a1.y);
                    int j0 = v << 6;
                    int jhi = min(64, nv - j0);
#pragma unroll 4
                    for (int jj = 0; jj < jhi; ++jj) {
                        float2 b1 = p1[j0 + jj], b2 = p2[j0 + jj];
                        float ty1 = fmaxf(a1.x, b1.x);
                        float tx1 = fmaxf(a1.y, b1.y);
                        float ty2 = fminf(a2.x, b2.x);
                        float tx2 = fminf(a2.y, b2.y);
                        float inter = fmaxf(ty2 - ty1, 0.f) * fmaxf(tx2 - tx1, 0.f);
                        float jarea = (b2.x - b1.x) * (b2.y - b1.y);
                        float uni = fmaxf(iarea + jarea - inter, 1e-10f);
                        if ((double)inter > IOU_MID * (double)uni) m |= 1ull << jj;
                    }
                    if (vr == 0)
                        m &= (il < 63) ? (~0ull << (il + 1)) : 0ull;
                }
            }
            chunk[il * 33 + vr] = m;
        }
        __syncthreads();

        u64 cand = chunk[lane * 33];
        u64 cur = rem[w];
        int remn = nv - (w << 6);
        u64 vb = (remn >= 64) ? ~0ull : ((1ull << remn) - 1ull);
        u64 avail = vb & ~cur;
        u64 kept = 0;
        while (avail) {
            int bb = __ffsll(avail) - 1;
            kept |= 1ull << bb;
            cur |= __shfl(cand, bb, 64);
            avail &= ~(cur | (1ull << bb));
        }
        int vr = t & 31, pg = t >> 5;
        if (vr >= 1 && vr < nwr) {
            u64 acc = 0, km = kept;
            int n = 0;
            while (km) {
                int bb = __ffsll(km) - 1;
                km &= km - 1;
                if ((n & 31) == pg) acc |= chunk[bb * 33 + vr];
                ++n;
            }
            if (acc) atomicOr(&rem[w + vr], acc);
        }
        if (t == 0) rem[w] = cur;
        __syncthreads();
    }

    u16* inv = (u16*)chunk;
    for (int r = t; r < R; r += NTH) inv[r] = 0xffffu;
    __syncthreads();
    for (int i = t; i < nv; i += NTH)
        if (!((rem[i >> 6] >> (i & 63)) & 1ull))
            inv[(int)(vkey[i] & 0xffffffffu)] = (u16)i;
    __syncthreads();
    float* slice = out + (size_t)(c - 1) * R * 5;
    for (int r = t; r < R; r += NTH) {
        int i = inv[r];
        float v0 = 0.f, v1 = 0.f, v2 = 0.f, v3 = 0.f, v4 = 0.f;
        if (i != 0xffff) {
            float2 a1 = p1[i], a2 = p2[i];
            v0 = a1.x; v1 = a1.y; v2 = a2.x; v3 = a2.y;
            v4 = __uint_as_float(~(u32)(vkey[i] >> 32));
        }
        float* p = slice + (size_t)r * 5;
        p[0] = v0; p[1] = v1; p[2] = v2; p[3] = v3; p[4] = v4;
    }
}

extern "C" void kernel_launch(void* const* d_in, const int* in_sizes, int n_in,
                              void* d_out, int out_size, void* d_ws, size_t ws_size,
                              hipStream_t stream) {
    const float* loc    = (const float*)d_in[0];   // (R, 84) f32
    const float* scores = (const float*)d_in[1];   // (R, 21) f32
    const float* rois   = (const float*)d_in[2];   // (R, 4)  f32
    const int*   ph     = (const int*)d_in[3];
    const int*   pw     = (const int*)d_in[4];
    float* out = (float*)d_out;                    // (20, R, 5) f32
    int R = in_sizes[2] / 4;

    // ws: M u64[20][2048*32] (compact) | ord u64[20][2048]
    size_t needM   = (size_t)NCO * RCAP * 32 * 8;  // 10.5 MB
    size_t needOrd = (size_t)NCO * RCAP * 8;       // 328 KB
    size_t need    = needM + needOrd + 128;

    if (R <= RCAP && ws_size >= need) {
        char* w   = (char*)d_ws;
        u64* M    = (u64*)w;
        u64* ordp = (u64*)(w + needM);
        fused_all_kernel<<<NCO, STH, 0, stream>>>(loc, scores, rois, ph, pw,
                                                  ordp, M, out, R);
    } else if (R <= RMAX) {
        fused_kernel<<<NCO, NTH, 0, stream>>>(loc, scores, rois, ph, pw, out, R);
    }
}